// Round 1
// baseline (572.663 us; speedup 1.0000x reference)
//
#include <hip/hip_runtime.h>
#include <math.h>

#define BB 64
#define NN 1024
#define HID 64
#define STATE 32
#define NTYPES 10

__device__ __forceinline__ float sigm(float x) { return 1.f / (1.f + expf(-x)); }

// ---------------- encoder: emb = relu(x@W1^T+b1)@W2^T+b2 ; nrm = emb/max(||emb||,1e-12)
__global__ __launch_bounds__(256) void k_encoder(
    const float* __restrict__ feat,
    const float* __restrict__ w1, const float* __restrict__ b1,
    const float* __restrict__ w2, const float* __restrict__ b2,
    float* __restrict__ emb, float* __restrict__ nrm)
{
    __shared__ float w2s[HID * 65];
    __shared__ float hids[4][HID];
    int tid = threadIdx.x;
    for (int i = tid; i < HID * HID; i += 256) w2s[(i >> 6) * 65 + (i & 63)] = w2[i];
    int wave = tid >> 6, lane = tid & 63;
    float w10 = w1[lane * 3], w11 = w1[lane * 3 + 1], w12 = w1[lane * 3 + 2];
    float b1l = b1[lane], b2l = b2[lane];
    __syncthreads();
    size_t base = (size_t)blockIdx.x * 32;
    for (int it = 0; it < 8; ++it) {
        size_t n = base + (size_t)wave * 8 + it;
        const float* x = feat + n * 3;
        float hv = fmaxf(fmaf(w10, x[0], fmaf(w11, x[1], fmaf(w12, x[2], b1l))), 0.f);
        hids[wave][lane] = hv;
        __syncthreads();
        float acc = b2l;
#pragma unroll
        for (int k = 0; k < HID; ++k)
            acc = fmaf(w2s[lane * 65 + k], hids[wave][k], acc);
        __syncthreads();
        float ss = acc * acc;
#pragma unroll
        for (int off = 32; off; off >>= 1) ss += __shfl_xor(ss, off, 64);
        float rinv = 1.f / fmaxf(sqrtf(ss), 1e-12f);
        emb[n * HID + lane] = acc;
        nrm[n * HID + lane] = acc * rinv;
    }
}

// ---------------- bucket tasks by type: idx[b][t][...], cnt[b][t]
__global__ __launch_bounds__(256) void k_bucket(
    const int* __restrict__ types, int* __restrict__ idx, int* __restrict__ cnt)
{
    int b = blockIdx.x;
    __shared__ int lcnt[NTYPES];
    if (threadIdx.x < NTYPES) lcnt[threadIdx.x] = 0;
    __syncthreads();
    for (int m = threadIdx.x; m < NN; m += 256) {
        int t = types[b * NN + m];
        int pos = atomicAdd(&lcnt[t], 1);
        idx[(b * NTYPES + t) * NN + pos] = m;
    }
    __syncthreads();
    if (threadIdx.x < NTYPES) cnt[b * NTYPES + threadIdx.x] = lcnt[threadIdx.x];
}

// ---------------- build M_j = sum_{m: t_m=j} nrm_m (outer) h_m   (64x64 per (b,j))
__global__ __launch_bounds__(256) void k_buildM(
    const int* __restrict__ idx, const int* __restrict__ cnt,
    const float* __restrict__ nrm, const float* __restrict__ h,
    float* __restrict__ M)
{
    int b = blockIdx.x / NTYPES, j = blockIdx.x % NTYPES;
    int c = cnt[b * NTYPES + j];
    const int* lst = idx + (b * NTYPES + j) * NN;
    int kq = threadIdx.x >> 4, dq = threadIdx.x & 15;
    float acc[4][4] = {};
    const float4* nrm4 = (const float4*)(nrm + (size_t)b * NN * HID);
    const float4* h4   = (const float4*)(h   + (size_t)b * NN * HID);
    int e = 0;
    for (; e + 4 <= c; e += 4) {
        int ms[4];
#pragma unroll
        for (int u = 0; u < 4; ++u) ms[u] = lst[e + u];
#pragma unroll
        for (int u = 0; u < 4; ++u) {
            float4 a  = nrm4[ms[u] * 16 + kq];
            float4 hh = h4[ms[u] * 16 + dq];
            float av[4] = {a.x, a.y, a.z, a.w};
            float hv[4] = {hh.x, hh.y, hh.z, hh.w};
#pragma unroll
            for (int i = 0; i < 4; ++i)
#pragma unroll
                for (int q = 0; q < 4; ++q)
                    acc[i][q] = fmaf(av[i], hv[q], acc[i][q]);
        }
    }
    for (; e < c; ++e) {
        int m = lst[e];
        float4 a  = nrm4[m * 16 + kq];
        float4 hh = h4[m * 16 + dq];
        float av[4] = {a.x, a.y, a.z, a.w};
        float hv[4] = {hh.x, hh.y, hh.z, hh.w};
#pragma unroll
        for (int i = 0; i < 4; ++i)
#pragma unroll
            for (int q = 0; q < 4; ++q)
                acc[i][q] = fmaf(av[i], hv[q], acc[i][q]);
    }
    float4* Mo = (float4*)(M + ((size_t)(b * NTYPES + j)) * HID * HID);
#pragma unroll
    for (int i = 0; i < 4; ++i)
        Mo[(kq * 4 + i) * 16 + dq] = make_float4(acc[i][0], acc[i][1], acc[i][2], acc[i][3]);
}

// ---------------- layer: C_t = sum_j sig(cont[t,j]) M_j (in LDS); per row m of type t:
//                  h_out = relu((h_m + nrm_m @ C_t) @ gw^T + gb)
__global__ __launch_bounds__(256) void k_gnn_layer(
    const int* __restrict__ idx, const int* __restrict__ cnt,
    const float* __restrict__ cont,
    const float* __restrict__ nrm, const float* __restrict__ h,
    const float* __restrict__ M,
    const float* __restrict__ gw, const float* __restrict__ gb,
    float* __restrict__ hout)
{
    __shared__ float Cs[HID * HID];
    __shared__ float gws[HID * 65];
    int b = blockIdx.x / NTYPES, t = blockIdx.x % NTYPES;
    int tid = threadIdx.x;
    for (int i = tid; i < HID * HID; i += 256) gws[(i >> 6) * 65 + (i & 63)] = gw[i];
    float sg[NTYPES];
#pragma unroll
    for (int j = 0; j < NTYPES; ++j) sg[j] = sigm(cont[t * NTYPES + j]);
    const float* Mb = M + (size_t)b * NTYPES * HID * HID;
    for (int p = tid; p < HID * HID; p += 256) {
        float a = 0.f;
#pragma unroll
        for (int j = 0; j < NTYPES; ++j) a = fmaf(sg[j], Mb[j * HID * HID + p], a);
        Cs[p] = a;
    }
    __syncthreads();
    int c = cnt[b * NTYPES + t];
    const int* lst = idx + (b * NTYPES + t) * NN;
    int wave = tid >> 6, lane = tid & 63;
    float gbl = gb[lane];
    const float* nb = nrm + (size_t)b * NN * HID;
    const float* hb = h + (size_t)b * NN * HID;
    float* ho = hout + (size_t)b * NN * HID;
    for (int e = wave; e < c; e += 4) {
        int m = lst[e];
        float nv = nb[m * HID + lane];
        float hv = hb[m * HID + lane];
        float agg = 0.f;
#pragma unroll
        for (int k = 0; k < HID; ++k)
            agg = fmaf(__shfl(nv, k, 64), Cs[k * HID + lane], agg);
        float tmp = hv + agg;
        float acc = gbl;
#pragma unroll
        for (int k = 0; k < HID; ++k)
            acc = fmaf(gws[lane * 65 + k], __shfl(tmp, k, 64), acc);
        ho[m * HID + lane] = fmaxf(acc, 0.f);
    }
}

// ---------------- ctx = mean_n h2 ; GRU -> new_state (written to d_out tail)
__global__ __launch_bounds__(256) void k_ctx_gru(
    const float* __restrict__ h2, const float* __restrict__ prev,
    const float* __restrict__ w_ih, const float* __restrict__ w_hh,
    const float* __restrict__ b_ih, const float* __restrict__ b_hh,
    float* __restrict__ state_out)
{
    int b = blockIdx.x;
    int tid = threadIdx.x;
    int d = tid & 63, g = tid >> 6;
    float s = 0.f;
    for (int n = g; n < NN; n += 4) s += h2[((size_t)b * NN + n) * HID + d];
    __shared__ float part[4][HID];
    __shared__ float cs[HID];
    __shared__ float gis[96], ghs[96];
    part[g][d] = s;
    __syncthreads();
    if (tid < HID)
        cs[tid] = (part[0][tid] + part[1][tid] + part[2][tid] + part[3][tid]) * (1.f / NN);
    __syncthreads();
    if (tid < 96) {
        float gi = b_ih[tid];
#pragma unroll 8
        for (int k = 0; k < HID; ++k) gi = fmaf(w_ih[tid * HID + k], cs[k], gi);
        float gh = b_hh[tid];
#pragma unroll
        for (int k = 0; k < STATE; ++k) gh = fmaf(w_hh[tid * STATE + k], prev[b * STATE + k], gh);
        gis[tid] = gi; ghs[tid] = gh;
    }
    __syncthreads();
    if (tid < STATE) {
        float r = sigm(gis[tid] + ghs[tid]);
        float z = sigm(gis[32 + tid] + ghs[32 + tid]);
        float nn = tanhf(gis[64 + tid] + r * ghs[64 + tid]);
        float pv = prev[b * STATE + tid];
        state_out[b * STATE + tid] = (1.f - z) * nn + z * pv;
    }
}

// ---------------- head: lat = relu([h2, st] @ W1^T + b1) @ W2^T + b2
__global__ __launch_bounds__(256) void k_head(
    const float* __restrict__ h2, const float* __restrict__ state,
    const float* __restrict__ w1, const float* __restrict__ b1,
    const float* __restrict__ w2, const float* __restrict__ b2,
    float* __restrict__ lat)
{
    __shared__ float w1s[HID * 97];
    __shared__ float st[STATE];
    int tid = threadIdx.x;
    for (int i = tid; i < HID * 96; i += 256) w1s[(i / 96) * 97 + (i % 96)] = w1[i];
    size_t base = (size_t)blockIdx.x * 32;
    int b = (int)(base >> 10);
    if (tid < STATE) st[tid] = state[b * STATE + tid];
    __syncthreads();
    int wave = tid >> 6, lane = tid & 63;
    float b1l = b1[lane], w2l = w2[lane], b2v = b2[0];
    for (int it = 0; it < 8; ++it) {
        size_t n = base + (size_t)wave * 8 + it;
        float hv = h2[n * HID + lane];
        float acc = b1l;
#pragma unroll
        for (int k = 0; k < HID; ++k)
            acc = fmaf(w1s[lane * 97 + k], __shfl(hv, k, 64), acc);
#pragma unroll
        for (int k = 0; k < STATE; ++k)
            acc = fmaf(w1s[lane * 97 + 64 + k], st[k], acc);
        float hid = fmaxf(acc, 0.f);
        float pv = w2l * hid;
#pragma unroll
        for (int off = 32; off; off >>= 1) pv += __shfl_xor(pv, off, 64);
        if (lane == 0) lat[n] = pv + b2v;
    }
}

extern "C" void kernel_launch(void* const* d_in, const int* in_sizes, int n_in,
                              void* d_out, int out_size, void* d_ws, size_t ws_size,
                              hipStream_t stream) {
    const float* feat   = (const float*)d_in[0];
    const int*   types  = (const int*)d_in[1];
    const float* prev   = (const float*)d_in[2];
    const float* enc_w1 = (const float*)d_in[3];
    const float* enc_b1 = (const float*)d_in[4];
    const float* enc_w2 = (const float*)d_in[5];
    const float* enc_b2 = (const float*)d_in[6];
    const float* cont   = (const float*)d_in[7];
    const float* gnn_w  = (const float*)d_in[8];
    const float* gnn_b  = (const float*)d_in[9];
    const float* w_ih   = (const float*)d_in[10];
    const float* w_hh   = (const float*)d_in[11];
    const float* b_ih   = (const float*)d_in[12];
    const float* b_hh   = (const float*)d_in[13];
    const float* hw1    = (const float*)d_in[14];
    const float* hb1    = (const float*)d_in[15];
    const float* hw2    = (const float*)d_in[16];
    const float* hb2    = (const float*)d_in[17];
    float* out = (float*)d_out;

    float* ws  = (float*)d_ws;
    float* emb = ws;                      // 4194304 floats (reused as h2)
    float* nrm = ws + 4194304;            // 4194304
    float* h1  = ws + 8388608;            // 4194304
    float* M   = ws + 12582912;           // B*10*64*64 = 2621440
    int*   idx = (int*)(ws + 15204352);   // B*10*1024 = 655360 ints
    int*   cnt = idx + BB * NTYPES * NN;  // 640 ints

    k_encoder<<<BB * NN / 32, 256, 0, stream>>>(feat, enc_w1, enc_b1, enc_w2, enc_b2, emb, nrm);
    k_bucket<<<BB, 256, 0, stream>>>(types, idx, cnt);
    // layer 0: h0 = emb
    k_buildM<<<BB * NTYPES, 256, 0, stream>>>(idx, cnt, nrm, emb, M);
    k_gnn_layer<<<BB * NTYPES, 256, 0, stream>>>(idx, cnt, cont, nrm, emb, M,
                                                 gnn_w, gnn_b, h1);
    // layer 1: h1 -> h2 (aliases emb; emb no longer needed)
    k_buildM<<<BB * NTYPES, 256, 0, stream>>>(idx, cnt, nrm, h1, M);
    k_gnn_layer<<<BB * NTYPES, 256, 0, stream>>>(idx, cnt, cont, nrm, h1, M,
                                                 gnn_w + HID * HID, gnn_b + HID, emb);
    // ctx mean + GRU -> new_state at out[B*N ...]
    k_ctx_gru<<<BB, 256, 0, stream>>>(emb, prev, w_ih, w_hh, b_ih, b_hh, out + BB * NN);
    // head reads h2 + state (already in d_out tail)
    k_head<<<BB * NN / 32, 256, 0, stream>>>(emb, out + BB * NN, hw1, hb1, hw2, hb2, out);
}

// Round 2
// 278.583 us; speedup vs baseline: 2.0556x; 2.0556x over previous
//
#include <hip/hip_runtime.h>
#include <math.h>

#define BB 64
#define NN 1024
#define HID 64
#define STATE 32
#define NTYPES 10

typedef _Float16 f16;
typedef f16 f16x8 __attribute__((ext_vector_type(8)));
typedef float f32x4 __attribute__((ext_vector_type(4)));

#define MFMA16(a, b, c) __builtin_amdgcn_mfma_f32_16x16x32_f16(a, b, c, 0, 0, 0)

__device__ __forceinline__ float sigm(float x) { return 1.f / (1.f + expf(-x)); }

__device__ __forceinline__ f16x8 cvt8(float4 a, float4 b) {
    f16x8 r;
    r[0] = (f16)a.x; r[1] = (f16)a.y; r[2] = (f16)a.z; r[3] = (f16)a.w;
    r[4] = (f16)b.x; r[5] = (f16)b.y; r[6] = (f16)b.z; r[7] = (f16)b.w;
    return r;
}

// ---------------- prep: swizzle weights into MFMA B-frag layout (f16)
// segments in out: [0,4096): enc_w2 | [4096,8192): gnn_w L0 | [8192,12288): gnn_w L1
//                  [12288,18432): head_w1 (K=96, 3 chunks)
__global__ __launch_bounds__(256) void k_prep(
    const float* __restrict__ w2, const float* __restrict__ gw,
    const float* __restrict__ hw1, f16* __restrict__ out)
{
    int p = blockIdx.x * 256 + threadIdx.x;
    if (p >= 18432) return;
    const float* W; int K, pl;
    if (p < 12288) { int seg = p >> 12; pl = p & 4095; W = (seg == 0) ? w2 : gw + (seg - 1) * 4096; K = 64; }
    else { W = hw1; K = 96; pl = p - 12288; }
    int j = pl & 7, lane = (pl >> 3) & 63, nt = (pl >> 9) & 3, ch = pl >> 11;
    int k = ch * 32 + ((lane >> 4) << 3) + j;
    int o = nt * 16 + (lane & 15);
    out[p] = (f16)W[o * K + k];
}

// ---------------- encoder (MFMA): emb = relu(x@W1^T+b1)@W2^T+b2 ; nrm = emb/||emb||
__global__ __launch_bounds__(256) void k_encoder(
    const float* __restrict__ feat,
    const float* __restrict__ w1, const float* __restrict__ b1,
    const f16* __restrict__ w2f, const float* __restrict__ b2,
    float* __restrict__ emb, float* __restrict__ nrm)
{
    __shared__ f16 w2s[4096];
    __shared__ f16 tmp[4][16 * 72];
    __shared__ float fbuf[4][48];
    int tid = threadIdx.x, wave = tid >> 6, lane = tid & 63;
    int l15 = lane & 15, quad = lane >> 4;
    { const uint4* s = (const uint4*)w2f; uint4* d = (uint4*)w2s;
      for (int i = tid; i < 512; i += 256) d[i] = s[i]; }
    float w10 = w1[lane * 3], w11 = w1[lane * 3 + 1], w12 = w1[lane * 3 + 2], b1l = b1[lane];
    int tb = blockIdx.x * 64 + wave * 16;
    if (lane < 48) fbuf[wave][lane] = feat[tb * 3 + lane];
    __syncthreads();
    f16* tw = &tmp[wave][0];
#pragma unroll
    for (int r = 0; r < 16; ++r) {
        float x0 = fbuf[wave][r * 3], x1 = fbuf[wave][r * 3 + 1], x2 = fbuf[wave][r * 3 + 2];
        float hv = fmaxf(fmaf(w10, x0, fmaf(w11, x1, fmaf(w12, x2, b1l))), 0.f);
        tw[r * 72 + lane] = (f16)hv;
    }
    __builtin_amdgcn_sched_barrier(0);
    f16x8 a0 = *(const f16x8*)&tw[l15 * 72 + quad * 8];
    f16x8 a1 = *(const f16x8*)&tw[l15 * 72 + 32 + quad * 8];
    const f16x8* bf = (const f16x8*)w2s;
    f32x4 acc[4];
#pragma unroll
    for (int nt = 0; nt < 4; ++nt) {
        f32x4 c = {0.f, 0.f, 0.f, 0.f};
        c = MFMA16(a0, bf[(0 * 4 + nt) * 64 + lane], c);
        c = MFMA16(a1, bf[(1 * 4 + nt) * 64 + lane], c);
        acc[nt] = c;
    }
    float b2c[4];
#pragma unroll
    for (int nt = 0; nt < 4; ++nt) b2c[nt] = b2[nt * 16 + l15];
#pragma unroll
    for (int i = 0; i < 4; ++i) {
        float v[4]; float ss = 0.f;
#pragma unroll
        for (int nt = 0; nt < 4; ++nt) { v[nt] = acc[nt][i] + b2c[nt]; ss = fmaf(v[nt], v[nt], ss); }
        ss += __shfl_xor(ss, 1, 64); ss += __shfl_xor(ss, 2, 64);
        ss += __shfl_xor(ss, 4, 64); ss += __shfl_xor(ss, 8, 64);
        float rinv = 1.f / fmaxf(sqrtf(ss), 1e-12f);
        int grow = tb + quad * 4 + i;
#pragma unroll
        for (int nt = 0; nt < 4; ++nt) {
            emb[grow * 64 + nt * 16 + l15] = v[nt];
            nrm[grow * 64 + nt * 16 + l15] = v[nt] * rinv;
        }
    }
}

// ---------------- bucket tasks by type
__global__ __launch_bounds__(256) void k_bucket(
    const int* __restrict__ types, int* __restrict__ idx, int* __restrict__ cnt)
{
    int b = blockIdx.x;
    __shared__ int lcnt[NTYPES];
    if (threadIdx.x < NTYPES) lcnt[threadIdx.x] = 0;
    __syncthreads();
    for (int m = threadIdx.x; m < NN; m += 256) {
        int t = types[b * NN + m];
        int pos = atomicAdd(&lcnt[t], 1);
        idx[(b * NTYPES + t) * NN + pos] = m;
    }
    __syncthreads();
    if (threadIdx.x < NTYPES) cnt[b * NTYPES + threadIdx.x] = lcnt[threadIdx.x];
}

// ---------------- build M_j = sum_{m: t_m=j} nrm_m (outer) h_m, stored f16
__global__ __launch_bounds__(256) void k_buildM(
    const int* __restrict__ idx, const int* __restrict__ cnt,
    const float* __restrict__ nrm, const float* __restrict__ h,
    f16* __restrict__ M)
{
    int b = blockIdx.x / NTYPES, j = blockIdx.x % NTYPES;
    int c = cnt[b * NTYPES + j];
    const int* lst = idx + (b * NTYPES + j) * NN;
    int kq = threadIdx.x >> 4, dq = threadIdx.x & 15;
    float acc[4][4] = {};
    const float4* nrm4 = (const float4*)(nrm + (size_t)b * NN * HID);
    const float4* h4   = (const float4*)(h   + (size_t)b * NN * HID);
    int e = 0;
    for (; e + 8 <= c; e += 8) {
        int ms[8];
#pragma unroll
        for (int u = 0; u < 8; ++u) ms[u] = lst[e + u];
        float4 av4[8], hv4[8];
#pragma unroll
        for (int u = 0; u < 8; ++u) { av4[u] = nrm4[ms[u] * 16 + kq]; hv4[u] = h4[ms[u] * 16 + dq]; }
#pragma unroll
        for (int u = 0; u < 8; ++u) {
            float av[4] = {av4[u].x, av4[u].y, av4[u].z, av4[u].w};
            float hv[4] = {hv4[u].x, hv4[u].y, hv4[u].z, hv4[u].w};
#pragma unroll
            for (int i = 0; i < 4; ++i)
#pragma unroll
                for (int q = 0; q < 4; ++q)
                    acc[i][q] = fmaf(av[i], hv[q], acc[i][q]);
        }
    }
    for (; e < c; ++e) {
        int m = lst[e];
        float4 a = nrm4[m * 16 + kq];
        float4 hh = h4[m * 16 + dq];
        float av[4] = {a.x, a.y, a.z, a.w};
        float hv[4] = {hh.x, hh.y, hh.z, hh.w};
#pragma unroll
        for (int i = 0; i < 4; ++i)
#pragma unroll
            for (int q = 0; q < 4; ++q)
                acc[i][q] = fmaf(av[i], hv[q], acc[i][q]);
    }
    f16* Mo = M + ((size_t)(b * NTYPES + j)) * HID * HID;
#pragma unroll
    for (int i = 0; i < 4; ++i) {
        union { f16 h[4]; uint2 u; } pk;
#pragma unroll
        for (int q = 0; q < 4; ++q) pk.h[q] = (f16)acc[i][q];
        *(uint2*)&Mo[(kq * 4 + i) * 64 + dq * 4] = pk.u;
    }
}

// ---------------- C_t = sum_j sig(cont[t,j]) M_j, emitted in B-frag layout (f16)
__global__ __launch_bounds__(256) void k_buildC(
    const float* __restrict__ cont, const f16* __restrict__ M, f16* __restrict__ Cfrag)
{
    int b = blockIdx.x / NTYPES, t = blockIdx.x % NTYPES;
    float sg[NTYPES];
#pragma unroll
    for (int j = 0; j < NTYPES; ++j) sg[j] = sigm(cont[t * NTYPES + j]);
    const f16* Mb = M + (size_t)b * NTYPES * 4096;
    f16* Co = Cfrag + (size_t)(b * NTYPES + t) * 4096;
    for (int p = threadIdx.x; p < 4096; p += 256) {
        float a = 0.f;
#pragma unroll
        for (int j = 0; j < NTYPES; ++j) a = fmaf(sg[j], (float)Mb[j * 4096 + p], a);
        int k = p >> 6, n = p & 63;
        int pos = (((k >> 5) * 4 + (n >> 4)) * 64 + ((k >> 3) & 3) * 16 + (n & 15)) * 8 + (k & 7);
        Co[pos] = (f16)a;
    }
}

// ---------------- GNN layer (MFMA): h_out = relu((h + nrm@C_t) @ gw^T + gb)
__global__ __launch_bounds__(256) void k_gnn_layer(
    const int* __restrict__ idx, const int* __restrict__ cnt,
    const f16* __restrict__ Cfrag,
    const float* __restrict__ nrm, const float* __restrict__ h,
    const f16* __restrict__ gwf, const float* __restrict__ gb,
    float* __restrict__ hout)
{
    __shared__ f16 cs[4096];
    __shared__ f16 gs[4096];
    __shared__ f16 tmp[4][16 * 72];
    int b = blockIdx.x / NTYPES, t = blockIdx.x % NTYPES;
    int c = cnt[b * NTYPES + t];
    if (c == 0) return;
    int tid = threadIdx.x, wave = tid >> 6, lane = tid & 63;
    int l15 = lane & 15, quad = lane >> 4;
    { const uint4* s1 = (const uint4*)(Cfrag + (size_t)(b * NTYPES + t) * 4096);
      const uint4* s2 = (const uint4*)gwf;
      uint4* d1 = (uint4*)cs; uint4* d2 = (uint4*)gs;
      for (int i = tid; i < 512; i += 256) { d1[i] = s1[i]; d2[i] = s2[i]; } }
    float gbl[4];
#pragma unroll
    for (int nt = 0; nt < 4; ++nt) gbl[nt] = gb[nt * 16 + l15];
    const int* lst = idx + (b * NTYPES + t) * NN;
    const float* nb = nrm + (size_t)b * NN * HID;
    const float* hb = h + (size_t)b * NN * HID;
    float* hob = hout + (size_t)b * NN * HID;
    __syncthreads();
    const f16x8* cbf = (const f16x8*)cs;
    const f16x8* gbf = (const f16x8*)gs;
    f16* tw = &tmp[wave][0];
    for (int tb = wave * 16; tb < c; tb += 64) {
        int rA = tb + l15; if (rA >= c) rA = c - 1;
        int mA = lst[rA];
        const float4* na = (const float4*)(nb + (size_t)mA * 64);
        f16x8 a0 = cvt8(na[quad * 2], na[quad * 2 + 1]);
        f16x8 a1 = cvt8(na[8 + quad * 2], na[8 + quad * 2 + 1]);
        int rS[4], mS[4]; float hl[4][4];
#pragma unroll
        for (int i = 0; i < 4; ++i) {
            rS[i] = tb + quad * 4 + i;
            int rc = rS[i] < c ? rS[i] : c - 1;
            mS[i] = lst[rc];
#pragma unroll
            for (int nt = 0; nt < 4; ++nt) hl[nt][i] = hb[(size_t)mS[i] * 64 + nt * 16 + l15];
        }
        f32x4 acc[4];
#pragma unroll
        for (int nt = 0; nt < 4; ++nt) {
            f32x4 cc = {0.f, 0.f, 0.f, 0.f};
            cc = MFMA16(a0, cbf[(0 * 4 + nt) * 64 + lane], cc);
            cc = MFMA16(a1, cbf[(1 * 4 + nt) * 64 + lane], cc);
            acc[nt] = cc;
        }
#pragma unroll
        for (int nt = 0; nt < 4; ++nt)
#pragma unroll
            for (int i = 0; i < 4; ++i)
                tw[(quad * 4 + i) * 72 + nt * 16 + l15] = (f16)(acc[nt][i] + hl[nt][i]);
        __builtin_amdgcn_sched_barrier(0);
        f16x8 t0 = *(const f16x8*)&tw[l15 * 72 + quad * 8];
        f16x8 t1 = *(const f16x8*)&tw[l15 * 72 + 32 + quad * 8];
#pragma unroll
        for (int nt = 0; nt < 4; ++nt) {
            f32x4 o = {0.f, 0.f, 0.f, 0.f};
            o = MFMA16(t0, gbf[(0 * 4 + nt) * 64 + lane], o);
            o = MFMA16(t1, gbf[(1 * 4 + nt) * 64 + lane], o);
#pragma unroll
            for (int i = 0; i < 4; ++i)
                if (rS[i] < c) hob[(size_t)mS[i] * 64 + nt * 16 + l15] = fmaxf(o[i] + gbl[nt], 0.f);
        }
        __builtin_amdgcn_sched_barrier(0);
    }
}

// ---------------- ctx mean + GRU -> new_state
__global__ __launch_bounds__(256) void k_ctx_gru(
    const float* __restrict__ h2, const float* __restrict__ prev,
    const float* __restrict__ w_ih, const float* __restrict__ w_hh,
    const float* __restrict__ b_ih, const float* __restrict__ b_hh,
    float* __restrict__ state_out)
{
    int b = blockIdx.x;
    int tid = threadIdx.x;
    int d = tid & 63, g = tid >> 6;
    float s = 0.f;
    for (int n = g; n < NN; n += 4) s += h2[((size_t)b * NN + n) * HID + d];
    __shared__ float part[4][HID];
    __shared__ float cs[HID];
    __shared__ float gis[96], ghs[96];
    part[g][d] = s;
    __syncthreads();
    if (tid < HID)
        cs[tid] = (part[0][tid] + part[1][tid] + part[2][tid] + part[3][tid]) * (1.f / NN);
    __syncthreads();
    if (tid < 96) {
        float gi = b_ih[tid];
#pragma unroll 8
        for (int k = 0; k < HID; ++k) gi = fmaf(w_ih[tid * HID + k], cs[k], gi);
        float gh = b_hh[tid];
#pragma unroll
        for (int k = 0; k < STATE; ++k) gh = fmaf(w_hh[tid * STATE + k], prev[b * STATE + k], gh);
        gis[tid] = gi; ghs[tid] = gh;
    }
    __syncthreads();
    if (tid < STATE) {
        float r = sigm(gis[tid] + ghs[tid]);
        float z = sigm(gis[32 + tid] + ghs[32 + tid]);
        float nn = tanhf(gis[64 + tid] + r * ghs[64 + tid]);
        float pv = prev[b * STATE + tid];
        state_out[b * STATE + tid] = (1.f - z) * nn + z * pv;
    }
}

// ---------------- head (MFMA): lat = relu([h2|st]@W1^T+b1)@w2 + b2
__global__ __launch_bounds__(256) void k_head(
    const float* __restrict__ h2, const float* __restrict__ state,
    const f16* __restrict__ hwf, const float* __restrict__ b1,
    const float* __restrict__ w2, const float* __restrict__ b2,
    float* __restrict__ lat)
{
    __shared__ f16 ws_[6144];
    int tid = threadIdx.x, wave = tid >> 6, lane = tid & 63;
    int l15 = lane & 15, quad = lane >> 4;
    int b = blockIdx.x >> 4;
    { const uint4* s = (const uint4*)hwf; uint4* d = (uint4*)ws_;
      for (int i = tid; i < 768; i += 256) d[i] = s[i]; }
    float b1c[4], w2c[4];
#pragma unroll
    for (int nt = 0; nt < 4; ++nt) { b1c[nt] = b1[nt * 16 + l15]; w2c[nt] = w2[nt * 16 + l15]; }
    float b2v = b2[0];
    __syncthreads();
    int tb = blockIdx.x * 64 + wave * 16;
    int grow = tb + l15;
    const float4* ha = (const float4*)(h2 + (size_t)grow * 64);
    f16x8 a0 = cvt8(ha[quad * 2], ha[quad * 2 + 1]);
    f16x8 a1 = cvt8(ha[8 + quad * 2], ha[8 + quad * 2 + 1]);
    const float4* sp = (const float4*)(state + b * STATE);
    f16x8 a2 = cvt8(sp[quad * 2], sp[quad * 2 + 1]);
    const f16x8* bf = (const f16x8*)ws_;
    f32x4 acc[4];
#pragma unroll
    for (int nt = 0; nt < 4; ++nt) {
        f32x4 cc = {0.f, 0.f, 0.f, 0.f};
        cc = MFMA16(a0, bf[(0 * 4 + nt) * 64 + lane], cc);
        cc = MFMA16(a1, bf[(1 * 4 + nt) * 64 + lane], cc);
        cc = MFMA16(a2, bf[(2 * 4 + nt) * 64 + lane], cc);
        acc[nt] = cc;
    }
#pragma unroll
    for (int i = 0; i < 4; ++i) {
        float s = 0.f;
#pragma unroll
        for (int nt = 0; nt < 4; ++nt) s = fmaf(fmaxf(acc[nt][i] + b1c[nt], 0.f), w2c[nt], s);
        s += __shfl_xor(s, 1, 64); s += __shfl_xor(s, 2, 64);
        s += __shfl_xor(s, 4, 64); s += __shfl_xor(s, 8, 64);
        if (l15 == 0) lat[tb + quad * 4 + i] = s + b2v;
    }
}

extern "C" void kernel_launch(void* const* d_in, const int* in_sizes, int n_in,
                              void* d_out, int out_size, void* d_ws, size_t ws_size,
                              hipStream_t stream) {
    const float* feat   = (const float*)d_in[0];
    const int*   types  = (const int*)d_in[1];
    const float* prev   = (const float*)d_in[2];
    const float* enc_w1 = (const float*)d_in[3];
    const float* enc_b1 = (const float*)d_in[4];
    const float* enc_w2 = (const float*)d_in[5];
    const float* enc_b2 = (const float*)d_in[6];
    const float* cont   = (const float*)d_in[7];
    const float* gnn_w  = (const float*)d_in[8];
    const float* gnn_b  = (const float*)d_in[9];
    const float* w_ih   = (const float*)d_in[10];
    const float* w_hh   = (const float*)d_in[11];
    const float* b_ih   = (const float*)d_in[12];
    const float* b_hh   = (const float*)d_in[13];
    const float* hw1    = (const float*)d_in[14];
    const float* hb1    = (const float*)d_in[15];
    const float* hw2    = (const float*)d_in[16];
    const float* hb2    = (const float*)d_in[17];
    float* out = (float*)d_out;

    float* ws  = (float*)d_ws;
    float* h0  = ws;                       // 4194304 floats (emb / h2)
    float* h1  = ws + 4194304;             // 4194304 floats (also hosts M for L0)
    float* nrm = ws + 8388608;             // 4194304 floats
    int*   idx = (int*)(ws + 12582912);    // 655360 ints
    int*   cnt = idx + BB * NTYPES * NN;   // 640 ints
    f16*   Cfrag = (f16*)(ws + 12582912 + 656000);            // 2621440 halfs
    f16*   wfrag = (f16*)(ws + 12582912 + 656000 + 1310720);  // 18432 halfs
    f16*   w2f  = wfrag;
    f16*   gw0f = wfrag + 4096;
    f16*   gw1f = wfrag + 8192;
    f16*   hwf  = wfrag + 12288;
    f16*   Mh0 = (f16*)h1;   // M for layer 0 (h1 dead until layer0 writes it)
    f16*   Mh1 = (f16*)h0;   // M for layer 1 (h0 dead after layer0; h2 overwrites later)

    k_prep<<<72, 256, 0, stream>>>(enc_w2, gnn_w, hw1, wfrag);
    k_encoder<<<BB * NN / 64, 256, 0, stream>>>(feat, enc_w1, enc_b1, w2f, enc_b2, h0, nrm);
    k_bucket<<<BB, 256, 0, stream>>>(types, idx, cnt);
    // layer 0: h = h0(emb) -> h1
    k_buildM<<<BB * NTYPES, 256, 0, stream>>>(idx, cnt, nrm, h0, Mh0);
    k_buildC<<<BB * NTYPES, 256, 0, stream>>>(cont, Mh0, Cfrag);
    k_gnn_layer<<<BB * NTYPES, 256, 0, stream>>>(idx, cnt, Cfrag, nrm, h0, gw0f, gnn_b, h1);
    // layer 1: h = h1 -> h2 (in h0 region)
    k_buildM<<<BB * NTYPES, 256, 0, stream>>>(idx, cnt, nrm, h1, Mh1);
    k_buildC<<<BB * NTYPES, 256, 0, stream>>>(cont, Mh1, Cfrag);
    k_gnn_layer<<<BB * NTYPES, 256, 0, stream>>>(idx, cnt, Cfrag, nrm, h1, gw1f, gnn_b + HID, h0);
    // ctx mean + GRU -> new_state (tail of d_out)
    k_ctx_gru<<<BB, 256, 0, stream>>>(h0, prev, w_ih, w_hh, b_ih, b_hh, out + BB * NN);
    // head
    k_head<<<BB * NN / 64, 256, 0, stream>>>(h0, out + BB * NN, hwf, hb1, hw2, hb2, out);
}

// Round 3
// 204.784 us; speedup vs baseline: 2.7964x; 1.3604x over previous
//
#include <hip/hip_runtime.h>
#include <math.h>

#define BB 64
#define NN 1024
#define HID 64
#define STATE 32
#define NTYPES 10

typedef _Float16 f16;
typedef f16 f16x8 __attribute__((ext_vector_type(8)));
typedef float f32x4 __attribute__((ext_vector_type(4)));

#define MFMA16(a, b, c) __builtin_amdgcn_mfma_f32_16x16x32_f16(a, b, c, 0, 0, 0)

__device__ __forceinline__ float sigm(float x) { return 1.f / (1.f + expf(-x)); }

__device__ __forceinline__ f16x8 cvt8(float4 a, float4 b) {
    f16x8 r;
    r[0] = (f16)a.x; r[1] = (f16)a.y; r[2] = (f16)a.z; r[3] = (f16)a.w;
    r[4] = (f16)b.x; r[5] = (f16)b.y; r[6] = (f16)b.z; r[7] = (f16)b.w;
    return r;
}

// ---------------- prep: swizzle weights into MFMA B-frag layout (f16)
// segments: [0,4096): enc_w2 | [4096,8192): gnn_w L0 | [8192,12288): gnn_w L1
//           [12288,18432): head_w1 (K=96, 3 chunks)
__global__ __launch_bounds__(256) void k_prep(
    const float* __restrict__ w2, const float* __restrict__ gw,
    const float* __restrict__ hw1, f16* __restrict__ out)
{
    int p = blockIdx.x * 256 + threadIdx.x;
    if (p >= 18432) return;
    const float* W; int K, pl;
    if (p < 12288) { int seg = p >> 12; pl = p & 4095; W = (seg == 0) ? w2 : gw + (seg - 1) * 4096; K = 64; }
    else { W = hw1; K = 96; pl = p - 12288; }
    int j = pl & 7, lane = (pl >> 3) & 63, nt = (pl >> 9) & 3, ch = pl >> 11;
    int k = ch * 32 + ((lane >> 4) << 3) + j;
    int o = nt * 16 + (lane & 15);
    out[p] = (f16)W[o * K + k];
}

// ---------------- encoder (MFMA): emb = relu(x@W1^T+b1)@W2^T+b2 ; nrm = emb/||emb||
__global__ __launch_bounds__(256) void k_encoder(
    const float* __restrict__ feat,
    const float* __restrict__ w1, const float* __restrict__ b1,
    const f16* __restrict__ w2f, const float* __restrict__ b2,
    float* __restrict__ emb, float* __restrict__ nrm)
{
    __shared__ f16 w2s[4096];
    __shared__ f16 tmp[4][16 * 72];
    __shared__ float fbuf[4][48];
    int tid = threadIdx.x, wave = tid >> 6, lane = tid & 63;
    int l15 = lane & 15, quad = lane >> 4;
    { const uint4* s = (const uint4*)w2f; uint4* d = (uint4*)w2s;
      for (int i = tid; i < 512; i += 256) d[i] = s[i]; }
    float w10 = w1[lane * 3], w11 = w1[lane * 3 + 1], w12 = w1[lane * 3 + 2], b1l = b1[lane];
    int tb = blockIdx.x * 64 + wave * 16;
    if (lane < 48) fbuf[wave][lane] = feat[tb * 3 + lane];
    __syncthreads();
    f16* tw = &tmp[wave][0];
#pragma unroll
    for (int r = 0; r < 16; ++r) {
        float x0 = fbuf[wave][r * 3], x1 = fbuf[wave][r * 3 + 1], x2 = fbuf[wave][r * 3 + 2];
        float hv = fmaxf(fmaf(w10, x0, fmaf(w11, x1, fmaf(w12, x2, b1l))), 0.f);
        tw[r * 72 + lane] = (f16)hv;
    }
    __builtin_amdgcn_sched_barrier(0);
    f16x8 a0 = *(const f16x8*)&tw[l15 * 72 + quad * 8];
    f16x8 a1 = *(const f16x8*)&tw[l15 * 72 + 32 + quad * 8];
    const f16x8* bf = (const f16x8*)w2s;
    f32x4 acc[4];
#pragma unroll
    for (int nt = 0; nt < 4; ++nt) {
        f32x4 c = {0.f, 0.f, 0.f, 0.f};
        c = MFMA16(a0, bf[(0 * 4 + nt) * 64 + lane], c);
        c = MFMA16(a1, bf[(1 * 4 + nt) * 64 + lane], c);
        acc[nt] = c;
    }
    float b2c[4];
#pragma unroll
    for (int nt = 0; nt < 4; ++nt) b2c[nt] = b2[nt * 16 + l15];
#pragma unroll
    for (int i = 0; i < 4; ++i) {
        float v[4]; float ss = 0.f;
#pragma unroll
        for (int nt = 0; nt < 4; ++nt) { v[nt] = acc[nt][i] + b2c[nt]; ss = fmaf(v[nt], v[nt], ss); }
        ss += __shfl_xor(ss, 1, 64); ss += __shfl_xor(ss, 2, 64);
        ss += __shfl_xor(ss, 4, 64); ss += __shfl_xor(ss, 8, 64);
        float rinv = 1.f / fmaxf(sqrtf(ss), 1e-12f);
        int grow = tb + quad * 4 + i;
#pragma unroll
        for (int nt = 0; nt < 4; ++nt) {
            emb[grow * 64 + nt * 16 + l15] = v[nt];
            nrm[grow * 64 + nt * 16 + l15] = v[nt] * rinv;
        }
    }
}

// ---------------- bucket tasks by type (also zeroes ctx accumulator)
__global__ __launch_bounds__(256) void k_bucket(
    const int* __restrict__ types, int* __restrict__ idx, int* __restrict__ cnt,
    float* __restrict__ ctx)
{
    int b = blockIdx.x;
    __shared__ int lcnt[NTYPES];
    if (threadIdx.x < NTYPES) lcnt[threadIdx.x] = 0;
    if (threadIdx.x < HID) ctx[b * HID + threadIdx.x] = 0.f;
    __syncthreads();
    for (int m = threadIdx.x; m < NN; m += 256) {
        int t = types[b * NN + m];
        int pos = atomicAdd(&lcnt[t], 1);
        idx[(b * NTYPES + t) * NN + pos] = m;
    }
    __syncthreads();
    if (threadIdx.x < NTYPES) cnt[b * NTYPES + threadIdx.x] = lcnt[threadIdx.x];
}

// ---------------- build M_j = sum_{m: t_m=j} nrm_m (outer) h_m, stored f16
__global__ __launch_bounds__(256) void k_buildM(
    const int* __restrict__ idx, const int* __restrict__ cnt,
    const float* __restrict__ nrm, const float* __restrict__ h,
    f16* __restrict__ M)
{
    int b = blockIdx.x / NTYPES, j = blockIdx.x % NTYPES;
    int c = cnt[b * NTYPES + j];
    const int* lst = idx + (b * NTYPES + j) * NN;
    int kq = threadIdx.x >> 4, dq = threadIdx.x & 15;
    float acc[4][4] = {};
    const float4* nrm4 = (const float4*)(nrm + (size_t)b * NN * HID);
    const float4* h4   = (const float4*)(h   + (size_t)b * NN * HID);
    int e = 0;
    for (; e + 8 <= c; e += 8) {
        int ms[8];
#pragma unroll
        for (int u = 0; u < 8; ++u) ms[u] = lst[e + u];
        float4 av4[8], hv4[8];
#pragma unroll
        for (int u = 0; u < 8; ++u) { av4[u] = nrm4[ms[u] * 16 + kq]; hv4[u] = h4[ms[u] * 16 + dq]; }
#pragma unroll
        for (int u = 0; u < 8; ++u) {
            float av[4] = {av4[u].x, av4[u].y, av4[u].z, av4[u].w};
            float hv[4] = {hv4[u].x, hv4[u].y, hv4[u].z, hv4[u].w};
#pragma unroll
            for (int i = 0; i < 4; ++i)
#pragma unroll
                for (int q = 0; q < 4; ++q)
                    acc[i][q] = fmaf(av[i], hv[q], acc[i][q]);
        }
    }
    for (; e < c; ++e) {
        int m = lst[e];
        float4 a = nrm4[m * 16 + kq];
        float4 hh = h4[m * 16 + dq];
        float av[4] = {a.x, a.y, a.z, a.w};
        float hv[4] = {hh.x, hh.y, hh.z, hh.w};
#pragma unroll
        for (int i = 0; i < 4; ++i)
#pragma unroll
            for (int q = 0; q < 4; ++q)
                acc[i][q] = fmaf(av[i], hv[q], acc[i][q]);
    }
    f16* Mo = M + ((size_t)(b * NTYPES + j)) * HID * HID;
#pragma unroll
    for (int i = 0; i < 4; ++i) {
        union { f16 h[4]; uint2 u; } pk;
#pragma unroll
        for (int q = 0; q < 4; ++q) pk.h[q] = (f16)acc[i][q];
        *(uint2*)&Mo[(kq * 4 + i) * 64 + dq * 4] = pk.u;
    }
}

// ---------------- GNN layer (MFMA): h_out = relu((h + nrm@C_t) @ gw^T + gb)
// C_t = sum_j sig(cont[t,j]) M_j built in LDS (B-frag layout).
// If ctx != nullptr, also accumulates column sums of h_out into ctx[b][:] (atomics).
__global__ __launch_bounds__(256) void k_gnn_layer(
    const int* __restrict__ idx, const int* __restrict__ cnt,
    const float* __restrict__ cont, const f16* __restrict__ M,
    const float* __restrict__ nrm, const float* __restrict__ h,
    const f16* __restrict__ gwf, const float* __restrict__ gb,
    float* __restrict__ hout, float* __restrict__ ctx)
{
    __shared__ f16 cs[4096];
    __shared__ f16 gs[4096];
    __shared__ f16 tmp[4][16 * 72];
    int b = blockIdx.x / NTYPES, t = blockIdx.x % NTYPES;
    int c = cnt[b * NTYPES + t];
    if (c == 0) return;
    int tid = threadIdx.x, wave = tid >> 6, lane = tid & 63;
    int l15 = lane & 15, quad = lane >> 4;
    { const uint4* s2 = (const uint4*)gwf; uint4* d2 = (uint4*)gs;
      for (int i = tid; i < 512; i += 256) d2[i] = s2[i]; }
    // build C_t in LDS, B-frag layout
    {
        float sg[NTYPES];
#pragma unroll
        for (int j = 0; j < NTYPES; ++j) sg[j] = sigm(cont[t * NTYPES + j]);
        const f16* Mb = M + (size_t)b * NTYPES * 4096;
        for (int p = tid; p < 4096; p += 256) {
            float a = 0.f;
#pragma unroll
            for (int j = 0; j < NTYPES; ++j) a = fmaf(sg[j], (float)Mb[j * 4096 + p], a);
            int k = p >> 6, n = p & 63;
            int pos = (((k >> 5) * 4 + (n >> 4)) * 64 + ((k >> 3) & 3) * 16 + (n & 15)) * 8 + (k & 7);
            cs[pos] = (f16)a;
        }
    }
    float gbl[4];
#pragma unroll
    for (int nt = 0; nt < 4; ++nt) gbl[nt] = gb[nt * 16 + l15];
    const int* lst = idx + (b * NTYPES + t) * NN;
    const float* nb = nrm + (size_t)b * NN * HID;
    const float* hb = h + (size_t)b * NN * HID;
    float* hob = hout + (size_t)b * NN * HID;
    __syncthreads();
    const f16x8* cbf = (const f16x8*)cs;
    const f16x8* gbf = (const f16x8*)gs;
    f16* tw = &tmp[wave][0];
    float cacc[4] = {0.f, 0.f, 0.f, 0.f};
    for (int tb = wave * 16; tb < c; tb += 64) {
        int rA = tb + l15; if (rA >= c) rA = c - 1;
        int mA = lst[rA];
        const float4* na = (const float4*)(nb + (size_t)mA * 64);
        f16x8 a0 = cvt8(na[quad * 2], na[quad * 2 + 1]);
        f16x8 a1 = cvt8(na[8 + quad * 2], na[8 + quad * 2 + 1]);
        int rS[4], mS[4]; float hl[4][4];
#pragma unroll
        for (int i = 0; i < 4; ++i) {
            rS[i] = tb + quad * 4 + i;
            int rc = rS[i] < c ? rS[i] : c - 1;
            mS[i] = lst[rc];
#pragma unroll
            for (int nt = 0; nt < 4; ++nt) hl[nt][i] = hb[(size_t)mS[i] * 64 + nt * 16 + l15];
        }
        f32x4 acc[4];
#pragma unroll
        for (int nt = 0; nt < 4; ++nt) {
            f32x4 cc = {0.f, 0.f, 0.f, 0.f};
            cc = MFMA16(a0, cbf[(0 * 4 + nt) * 64 + lane], cc);
            cc = MFMA16(a1, cbf[(1 * 4 + nt) * 64 + lane], cc);
            acc[nt] = cc;
        }
#pragma unroll
        for (int nt = 0; nt < 4; ++nt)
#pragma unroll
            for (int i = 0; i < 4; ++i)
                tw[(quad * 4 + i) * 72 + nt * 16 + l15] = (f16)(acc[nt][i] + hl[nt][i]);
        __builtin_amdgcn_sched_barrier(0);
        f16x8 t0 = *(const f16x8*)&tw[l15 * 72 + quad * 8];
        f16x8 t1 = *(const f16x8*)&tw[l15 * 72 + 32 + quad * 8];
#pragma unroll
        for (int nt = 0; nt < 4; ++nt) {
            f32x4 o = {0.f, 0.f, 0.f, 0.f};
            o = MFMA16(t0, gbf[(0 * 4 + nt) * 64 + lane], o);
            o = MFMA16(t1, gbf[(1 * 4 + nt) * 64 + lane], o);
#pragma unroll
            for (int i = 0; i < 4; ++i)
                if (rS[i] < c) {
                    float v = fmaxf(o[i] + gbl[nt], 0.f);
                    hob[(size_t)mS[i] * 64 + nt * 16 + l15] = v;
                    cacc[nt] += v;
                }
        }
        __builtin_amdgcn_sched_barrier(0);
    }
    if (ctx) {
#pragma unroll
        for (int nt = 0; nt < 4; ++nt) {
            float s = cacc[nt];
            s += __shfl_xor(s, 16, 64);
            s += __shfl_xor(s, 32, 64);
            if (quad == 0) atomicAdd(&ctx[b * HID + nt * 16 + l15], s);
        }
    }
}

// ---------------- GRU from ctx sums -> new_state
__global__ __launch_bounds__(128) void k_gru(
    const float* __restrict__ ctx_sum, const float* __restrict__ prev,
    const float* __restrict__ w_ih, const float* __restrict__ w_hh,
    const float* __restrict__ b_ih, const float* __restrict__ b_hh,
    float* __restrict__ state_out)
{
    int b = blockIdx.x;
    int tid = threadIdx.x;
    __shared__ float cs[HID], ps[STATE], gis[96], ghs[96];
    if (tid < HID) cs[tid] = ctx_sum[b * HID + tid] * (1.f / NN);
    if (tid >= HID && tid < HID + STATE) ps[tid - HID] = prev[b * STATE + tid - HID];
    __syncthreads();
    if (tid < 96) {
        float gi = b_ih[tid];
#pragma unroll 8
        for (int k = 0; k < HID; ++k) gi = fmaf(w_ih[tid * HID + k], cs[k], gi);
        float gh = b_hh[tid];
#pragma unroll
        for (int k = 0; k < STATE; ++k) gh = fmaf(w_hh[tid * STATE + k], ps[k], gh);
        gis[tid] = gi; ghs[tid] = gh;
    }
    __syncthreads();
    if (tid < STATE) {
        float r = sigm(gis[tid] + ghs[tid]);
        float z = sigm(gis[32 + tid] + ghs[32 + tid]);
        float nn = tanhf(gis[64 + tid] + r * ghs[64 + tid]);
        float pv = ps[tid];
        state_out[b * STATE + tid] = (1.f - z) * nn + z * pv;
    }
}

// ---------------- head (MFMA): lat = relu([h2|st]@W1^T+b1)@w2 + b2
__global__ __launch_bounds__(256) void k_head(
    const float* __restrict__ h2, const float* __restrict__ state,
    const f16* __restrict__ hwf, const float* __restrict__ b1,
    const float* __restrict__ w2, const float* __restrict__ b2,
    float* __restrict__ lat)
{
    __shared__ f16 ws_[6144];
    int tid = threadIdx.x, wave = tid >> 6, lane = tid & 63;
    int l15 = lane & 15, quad = lane >> 4;
    int b = blockIdx.x >> 4;
    { const uint4* s = (const uint4*)hwf; uint4* d = (uint4*)ws_;
      for (int i = tid; i < 768; i += 256) d[i] = s[i]; }
    float b1c[4], w2c[4];
#pragma unroll
    for (int nt = 0; nt < 4; ++nt) { b1c[nt] = b1[nt * 16 + l15]; w2c[nt] = w2[nt * 16 + l15]; }
    float b2v = b2[0];
    __syncthreads();
    int tb = blockIdx.x * 64 + wave * 16;
    int grow = tb + l15;
    const float4* ha = (const float4*)(h2 + (size_t)grow * 64);
    f16x8 a0 = cvt8(ha[quad * 2], ha[quad * 2 + 1]);
    f16x8 a1 = cvt8(ha[8 + quad * 2], ha[8 + quad * 2 + 1]);
    const float4* sp = (const float4*)(state + b * STATE);
    f16x8 a2 = cvt8(sp[quad * 2], sp[quad * 2 + 1]);
    const f16x8* bf = (const f16x8*)ws_;
    f32x4 acc[4];
#pragma unroll
    for (int nt = 0; nt < 4; ++nt) {
        f32x4 cc = {0.f, 0.f, 0.f, 0.f};
        cc = MFMA16(a0, bf[(0 * 4 + nt) * 64 + lane], cc);
        cc = MFMA16(a1, bf[(1 * 4 + nt) * 64 + lane], cc);
        cc = MFMA16(a2, bf[(2 * 4 + nt) * 64 + lane], cc);
        acc[nt] = cc;
    }
#pragma unroll
    for (int i = 0; i < 4; ++i) {
        float s = 0.f;
#pragma unroll
        for (int nt = 0; nt < 4; ++nt) s = fmaf(fmaxf(acc[nt][i] + b1c[nt], 0.f), w2c[nt], s);
        s += __shfl_xor(s, 1, 64); s += __shfl_xor(s, 2, 64);
        s += __shfl_xor(s, 4, 64); s += __shfl_xor(s, 8, 64);
        if (l15 == 0) lat[tb + quad * 4 + i] = s + b2v;
    }
}

extern "C" void kernel_launch(void* const* d_in, const int* in_sizes, int n_in,
                              void* d_out, int out_size, void* d_ws, size_t ws_size,
                              hipStream_t stream) {
    const float* feat   = (const float*)d_in[0];
    const int*   types  = (const int*)d_in[1];
    const float* prev   = (const float*)d_in[2];
    const float* enc_w1 = (const float*)d_in[3];
    const float* enc_b1 = (const float*)d_in[4];
    const float* enc_w2 = (const float*)d_in[5];
    const float* enc_b2 = (const float*)d_in[6];
    const float* cont   = (const float*)d_in[7];
    const float* gnn_w  = (const float*)d_in[8];
    const float* gnn_b  = (const float*)d_in[9];
    const float* w_ih   = (const float*)d_in[10];
    const float* w_hh   = (const float*)d_in[11];
    const float* b_ih   = (const float*)d_in[12];
    const float* b_hh   = (const float*)d_in[13];
    const float* hw1    = (const float*)d_in[14];
    const float* hb1    = (const float*)d_in[15];
    const float* hw2    = (const float*)d_in[16];
    const float* hb2    = (const float*)d_in[17];
    float* out = (float*)d_out;

    float* ws  = (float*)d_ws;
    float* h0  = ws;                       // 4194304 floats (emb / h2)
    float* h1  = ws + 4194304;             // 4194304 floats
    float* nrm = ws + 8388608;             // 4194304 floats
    int*   idx = (int*)(ws + 12582912);    // 655360 ints
    int*   cnt = idx + BB * NTYPES * NN;   // 640 ints
    f16*   M    = (f16*)(ws + 12582912 + 656000);             // 2621440 halfs
    f16*   wfrag = (f16*)(ws + 12582912 + 656000 + 1310720);  // 18432 halfs
    float* ctx  = ws + 12582912 + 656000 + 1310720 + 9216;    // 4096 floats
    f16*   w2f  = wfrag;
    f16*   gw0f = wfrag + 4096;
    f16*   gw1f = wfrag + 8192;
    f16*   hwf  = wfrag + 12288;

    k_prep<<<72, 256, 0, stream>>>(enc_w2, gnn_w, hw1, wfrag);
    k_encoder<<<BB * NN / 64, 256, 0, stream>>>(feat, enc_w1, enc_b1, w2f, enc_b2, h0, nrm);
    k_bucket<<<BB, 256, 0, stream>>>(types, idx, cnt, ctx);
    // layer 0: h = h0(emb) -> h1
    k_buildM<<<BB * NTYPES, 256, 0, stream>>>(idx, cnt, nrm, h0, M);
    k_gnn_layer<<<BB * NTYPES, 256, 0, stream>>>(idx, cnt, cont, M, nrm, h0, gw0f, gnn_b, h1, nullptr);
    // layer 1: h = h1 -> h2 (in h0 region), fused ctx column-sum accumulation
    k_buildM<<<BB * NTYPES, 256, 0, stream>>>(idx, cnt, nrm, h1, M);
    k_gnn_layer<<<BB * NTYPES, 256, 0, stream>>>(idx, cnt, cont, M, nrm, h1, gw1f, gnn_b + HID, h0, ctx);
    // GRU -> new_state (tail of d_out)
    k_gru<<<BB, 128, 0, stream>>>(ctx, prev, w_ih, w_hh, b_ih, b_hh, out + BB * NN);
    // head
    k_head<<<BB * NN / 64, 256, 0, stream>>>(h0, out + BB * NN, hwf, hb1, hw2, hb2, out);
}